// Round 21
// baseline (247.727 us; speedup 1.0000x reference)
//
#include <hip/hip_runtime.h>
#include <stdint.h>
#include <stddef.h>

#define HEADS 8
#define DH 32
#define DMODEL 256
#define LN_EPS 1e-5f
#define LOG2E 1.4426950408889634f
#define QSCALE 0.17677669529663687f       // 1/sqrt(32)
#define QSCALE2 (QSCALE * LOG2E)          // folded: exp2 domain
#define EXP2(x) __builtin_amdgcn_exp2f(x) // v_exp_f32 (base-2 native)

typedef unsigned short u16;
typedef __bf16 bf16x8 __attribute__((ext_vector_type(8)));
typedef unsigned short u16x8 __attribute__((ext_vector_type(8)));
typedef float f32x4 __attribute__((ext_vector_type(4)));

static __device__ __forceinline__ u16 bfc(float f) {          // hw cvt (RNE)
    return __builtin_bit_cast(u16, (__bf16)f);
}
static __device__ __forceinline__ float bf2f(u16 v) {
    union { uint32_t u; float f; } t; t.u = (uint32_t)v << 16; return t.f;
}
static __device__ __forceinline__ bf16x8 ldbf8(const u16* p) {
    return __builtin_bit_cast(bf16x8, *reinterpret_cast<const u16x8*>(p));
}
static __device__ __forceinline__ bf16x8 cvt8(float4 a, float4 b) {
    bf16x8 r;
    r[0] = (__bf16)a.x; r[1] = (__bf16)a.y; r[2] = (__bf16)a.z; r[3] = (__bf16)a.w;
    r[4] = (__bf16)b.x; r[5] = (__bf16)b.y; r[6] = (__bf16)b.z; r[7] = (__bf16)b.w;
    return r;
}

// ---------------- mask pre-scale: out = in * log2e ----------------
__global__ __launch_bounds__(256) void scale_mask(const float* __restrict__ in,
                                                  float* __restrict__ out, int n) {
    int i = blockIdx.x * 256 + threadIdx.x;
    if (i < n) out[i] = in[i] * LOG2E;
}

// ---------------- batched transpose + convert: W[K][N] -> Wt[N][K] bf16 ----------------
struct TDesc { const float* src; u16* dst; int K; int N; };
struct TArgs { TDesc d[10]; };

__global__ __launch_bounds__(256) void transpose_cvt(TArgs args) {
    TDesc d = args.d[blockIdx.y];
    const int ntx = d.N >> 5;
    const int tiles = (d.K >> 5) * ntx;
    if ((int)blockIdx.x >= tiles) return;
    const int tk = (blockIdx.x / ntx) << 5;
    const int tn = (blockIdx.x % ntx) << 5;
    __shared__ float t[32][33];
    const int lx = threadIdx.x & 31;
    const int ly = threadIdx.x >> 5;
#pragma unroll
    for (int i = 0; i < 4; ++i)
        t[ly + 8 * i][lx] = d.src[(size_t)(tk + ly + 8 * i) * d.N + tn + lx];
    __syncthreads();
#pragma unroll
    for (int i = 0; i < 4; ++i)
        d.dst[(size_t)(tn + ly + 8 * i) * d.K + tk + lx] = bfc(t[lx][ly + 8 * i]);
}

// ---------------- fused projection GEMM: f32 A -> up to 3 output slices (m-fastest) ----------------
struct Slice { u16* out; const float* bias; int mode; float sc; };

__global__ __launch_bounds__(256) void gemm_xproj(
    const float* __restrict__ Af, const u16* __restrict__ Wt,
    Slice s0, Slice s1, Slice s2, int M, int ntm)
{
    const int lane = threadIdx.x & 63;
    const int wave = threadIdx.x >> 6;
    const int l15 = lane & 15, lhi = lane >> 4;
    const int tm = ((int)blockIdx.x % ntm) * 128;
    const int tn = ((int)blockIdx.x / ntm) * 64;
    const int wm = tm + wave * 32;
    const int sel = tn >> 8;
    const int tl = tn & 255;
    Slice sl = (sel == 0) ? s0 : (sel == 1 ? s1 : s2);

    const f32x4 z4 = {0.f, 0.f, 0.f, 0.f};
    f32x4 acc[2][4];
#pragma unroll
    for (int i = 0; i < 2; ++i)
#pragma unroll
        for (int j = 0; j < 4; ++j) acc[i][j] = z4;

    const float* ar0 = Af + (size_t)(wm + l15) * 256 + lhi * 8;
    const float* ar1 = ar0 + (size_t)16 * 256;
    const u16* b0p = Wt + (size_t)(tn + l15) * 256 + lhi * 8;

    float4 a00 = *(const float4*)(ar0), a01 = *(const float4*)(ar0 + 4);
    float4 a10 = *(const float4*)(ar1), a11 = *(const float4*)(ar1 + 4);
    bf16x8 b[4];
#pragma unroll
    for (int j = 0; j < 4; ++j) b[j] = ldbf8(b0p + (size_t)j * 16 * 256);

#pragma unroll
    for (int k = 32; k < 256; k += 32) {
        float4 n00 = *(const float4*)(ar0 + k), n01 = *(const float4*)(ar0 + k + 4);
        float4 n10 = *(const float4*)(ar1 + k), n11 = *(const float4*)(ar1 + k + 4);
        bf16x8 bn[4];
#pragma unroll
        for (int j = 0; j < 4; ++j) bn[j] = ldbf8(b0p + (size_t)j * 16 * 256 + k);
        bf16x8 a0 = cvt8(a00, a01), a1 = cvt8(a10, a11);
#pragma unroll
        for (int j = 0; j < 4; ++j) {
            acc[0][j] = __builtin_amdgcn_mfma_f32_16x16x32_bf16(a0, b[j], acc[0][j], 0, 0, 0);
            acc[1][j] = __builtin_amdgcn_mfma_f32_16x16x32_bf16(a1, b[j], acc[1][j], 0, 0, 0);
        }
        a00 = n00; a01 = n01; a10 = n10; a11 = n11;
#pragma unroll
        for (int j = 0; j < 4; ++j) b[j] = bn[j];
    }
    {
        bf16x8 a0 = cvt8(a00, a01), a1 = cvt8(a10, a11);
#pragma unroll
        for (int j = 0; j < 4; ++j) {
            acc[0][j] = __builtin_amdgcn_mfma_f32_16x16x32_bf16(a0, b[j], acc[0][j], 0, 0, 0);
            acc[1][j] = __builtin_amdgcn_mfma_f32_16x16x32_bf16(a1, b[j], acc[1][j], 0, 0, 0);
        }
    }

#pragma unroll
    for (int i = 0; i < 2; ++i) {
#pragma unroll
        for (int j = 0; j < 4; ++j) {
            const int col = tl + j * 16 + l15;
            const float bv = sl.bias[col];
            const int row0 = wm + i * 16 + lhi * 4;
            if (sl.mode == 1) {
#pragma unroll
                for (int r = 0; r < 4; ++r)
                    sl.out[(size_t)(row0 + r) * 256 + col] = bfc((acc[i][j][r] + bv) * sl.sc);
            } else {
                ushort4 o = make_ushort4(bfc((acc[i][j][0] + bv) * sl.sc), bfc((acc[i][j][1] + bv) * sl.sc),
                                         bfc((acc[i][j][2] + bv) * sl.sc), bfc((acc[i][j][3] + bv) * sl.sc));
                *reinterpret_cast<ushort4*>(sl.out + (size_t)col * M + row0) = o;
            }
        }
    }
}

// ---------------- WIDE GEMM: 128x128 tile, wave = 32x128 (16 MFMA : 10 loads) ----------------
template<int MODE, bool RELU>
__global__ __launch_bounds__(256) void gemm_wide(
    const u16* __restrict__ A, const u16* __restrict__ Bt,
    const float* __restrict__ bias, void* __restrict__ Cout,
    int M, int N, int K, int ntm, float osc)
{
    const int lane = threadIdx.x & 63;
    const int wave = threadIdx.x >> 6;
    const int l15 = lane & 15, lhi = lane >> 4;
    const int tm = ((int)blockIdx.x % ntm) * 128;
    const int tn = ((int)blockIdx.x / ntm) * 128;
    const int wm = tm + wave * 32;

    const f32x4 z4 = {0.f, 0.f, 0.f, 0.f};
    f32x4 acc[2][8];
#pragma unroll
    for (int i = 0; i < 2; ++i)
#pragma unroll
        for (int j = 0; j < 8; ++j) acc[i][j] = z4;

    const u16* a0p = A + (size_t)(wm + l15) * K + lhi * 8;
    const u16* a1p = a0p + (size_t)16 * K;
    const u16* b0p = Bt + (size_t)(tn + l15) * K + lhi * 8;

    bf16x8 a0 = ldbf8(a0p), a1 = ldbf8(a1p);
    bf16x8 b[8];
#pragma unroll
    for (int j = 0; j < 8; ++j) b[j] = ldbf8(b0p + (size_t)j * 16 * K);

    for (int k = 32; k < K; k += 32) {
        bf16x8 a0n = ldbf8(a0p + k), a1n = ldbf8(a1p + k);
        bf16x8 bn[8];
#pragma unroll
        for (int j = 0; j < 8; ++j) bn[j] = ldbf8(b0p + (size_t)j * 16 * K + k);
#pragma unroll
        for (int j = 0; j < 8; ++j) {
            acc[0][j] = __builtin_amdgcn_mfma_f32_16x16x32_bf16(a0, b[j], acc[0][j], 0, 0, 0);
            acc[1][j] = __builtin_amdgcn_mfma_f32_16x16x32_bf16(a1, b[j], acc[1][j], 0, 0, 0);
        }
        a0 = a0n; a1 = a1n;
#pragma unroll
        for (int j = 0; j < 8; ++j) b[j] = bn[j];
    }
#pragma unroll
    for (int j = 0; j < 8; ++j) {
        acc[0][j] = __builtin_amdgcn_mfma_f32_16x16x32_bf16(a0, b[j], acc[0][j], 0, 0, 0);
        acc[1][j] = __builtin_amdgcn_mfma_f32_16x16x32_bf16(a1, b[j], acc[1][j], 0, 0, 0);
    }

#pragma unroll
    for (int i = 0; i < 2; ++i) {
#pragma unroll
        for (int j = 0; j < 8; ++j) {
            const int col = tn + j * 16 + l15;
            const float bv = bias[col];
            const int row0 = wm + i * 16 + lhi * 4;
            if (MODE == 0) {
                float* C = (float*)Cout;
#pragma unroll
                for (int r = 0; r < 4; ++r) {
                    float v = acc[i][j][r] + bv;
                    if (RELU) v = fmaxf(v, 0.f);
                    C[(size_t)(row0 + r) * N + col] = v;
                }
            } else {
                u16* C = (u16*)Cout;
#pragma unroll
                for (int r = 0; r < 4; ++r) {
                    float v = acc[i][j][r] + bv;
                    if (RELU) v = fmaxf(v, 0.f);
                    C[(size_t)(row0 + r) * N + col] = bfc(v * osc);
                }
            }
        }
    }
}

// ---------------- split-K4 GEMM (FFN2): 128x64 tile, dist-2, 1024 blocks (4/CU) ----------------
// Quarter q computes K[q*Kh : (q+1)*Kh] into bf16 partial buffer q (bias on q==0 only).
__global__ __launch_bounds__(256) void gemm_sk4(
    const u16* __restrict__ A, const u16* __restrict__ Bt,
    const float* __restrict__ bias, u16* __restrict__ Cout,
    int M, int N, int lda, int Kh, int ntm)
{
    const int quarter = ntm * (N / 64);
    const int kh = (int)blockIdx.x / quarter;       // 0..3
    const int bid = (int)blockIdx.x % quarter;
    const int lane = threadIdx.x & 63;
    const int wave = threadIdx.x >> 6;
    const int l15 = lane & 15, lhi = lane >> 4;
    const int tm = (bid % ntm) * 128;
    const int tn = (bid / ntm) * 64;
    const int wm = tm + wave * 32;

    const f32x4 z4 = {0.f, 0.f, 0.f, 0.f};
    f32x4 acc[2][4];
#pragma unroll
    for (int i = 0; i < 2; ++i)
#pragma unroll
        for (int j = 0; j < 4; ++j) acc[i][j] = z4;

    const u16* a0p = A + (size_t)(wm + l15) * lda + kh * Kh + lhi * 8;
    const u16* a1p = a0p + (size_t)16 * lda;
    const u16* b0p = Bt + (size_t)(tn + l15) * lda + kh * Kh + lhi * 8;

    // distance-2: two named load sets over a 64-K unroll (8-acc ILP preserved)
    bf16x8 aA0 = ldbf8(a0p), aA1 = ldbf8(a1p);
    bf16x8 bA[4];
#pragma unroll
    for (int j = 0; j < 4; ++j) bA[j] = ldbf8(b0p + (size_t)j * 16 * lda);
    bf16x8 aB0 = ldbf8(a0p + 32), aB1 = ldbf8(a1p + 32);
    bf16x8 bB[4];
#pragma unroll
    for (int j = 0; j < 4; ++j) bB[j] = ldbf8(b0p + (size_t)j * 16 * lda + 32);

    for (int k = 64; k < Kh; k += 64) {
#pragma unroll
        for (int j = 0; j < 4; ++j) {
            acc[0][j] = __builtin_amdgcn_mfma_f32_16x16x32_bf16(aA0, bA[j], acc[0][j], 0, 0, 0);
            acc[1][j] = __builtin_amdgcn_mfma_f32_16x16x32_bf16(aA1, bA[j], acc[1][j], 0, 0, 0);
        }
        aA0 = ldbf8(a0p + k); aA1 = ldbf8(a1p + k);
#pragma unroll
        for (int j = 0; j < 4; ++j) bA[j] = ldbf8(b0p + (size_t)j * 16 * lda + k);
#pragma unroll
        for (int j = 0; j < 4; ++j) {
            acc[0][j] = __builtin_amdgcn_mfma_f32_16x16x32_bf16(aB0, bB[j], acc[0][j], 0, 0, 0);
            acc[1][j] = __builtin_amdgcn_mfma_f32_16x16x32_bf16(aB1, bB[j], acc[1][j], 0, 0, 0);
        }
        aB0 = ldbf8(a0p + k + 32); aB1 = ldbf8(a1p + k + 32);
#pragma unroll
        for (int j = 0; j < 4; ++j) bB[j] = ldbf8(b0p + (size_t)j * 16 * lda + k + 32);
    }
#pragma unroll
    for (int j = 0; j < 4; ++j) {
        acc[0][j] = __builtin_amdgcn_mfma_f32_16x16x32_bf16(aA0, bA[j], acc[0][j], 0, 0, 0);
        acc[1][j] = __builtin_amdgcn_mfma_f32_16x16x32_bf16(aA1, bA[j], acc[1][j], 0, 0, 0);
    }
#pragma unroll
    for (int j = 0; j < 4; ++j) {
        acc[0][j] = __builtin_amdgcn_mfma_f32_16x16x32_bf16(aB0, bB[j], acc[0][j], 0, 0, 0);
        acc[1][j] = __builtin_amdgcn_mfma_f32_16x16x32_bf16(aB1, bB[j], acc[1][j], 0, 0, 0);
    }

    u16* C = Cout + (size_t)kh * M * N;
    const float bs = (kh == 0) ? 1.f : 0.f;
#pragma unroll
    for (int i = 0; i < 2; ++i) {
#pragma unroll
        for (int j = 0; j < 4; ++j) {
            const int col = tn + j * 16 + l15;
            const float bv = bias[col] * bs;
            const int row0 = wm + i * 16 + lhi * 4;
#pragma unroll
            for (int r = 0; r < 4; ++r)
                C[(size_t)(row0 + r) * N + col] = bfc(acc[i][j][r] + bv);
        }
    }
}

// ---------------- LN over (sum of 4 bf16 partials + f32 residual) -> f32 out ----------------
__global__ __launch_bounds__(256) void ln_sum4(
    const u16* __restrict__ P, const float* __restrict__ Res,
    const float* __restrict__ gp, const float* __restrict__ bp,
    float* __restrict__ Of, int MN)
{
    const int lane = threadIdx.x & 63;
    const int row = blockIdx.x * 4 + (threadIdx.x >> 6);
    const size_t base = (size_t)row * DMODEL + lane * 4;
    float4 rr = *reinterpret_cast<const float4*>(Res + base);
    float v[4] = {rr.x, rr.y, rr.z, rr.w};
#pragma unroll
    for (int q = 0; q < 4; ++q) {
        ushort4 x = *reinterpret_cast<const ushort4*>(P + (size_t)q * MN + base);
        v[0] += bf2f(x.x); v[1] += bf2f(x.y); v[2] += bf2f(x.z); v[3] += bf2f(x.w);
    }
    float s = v[0] + v[1] + v[2] + v[3];
    float q2 = v[0] * v[0] + v[1] * v[1] + v[2] * v[2] + v[3] * v[3];
#pragma unroll
    for (int m = 1; m < 64; m <<= 1) { s += __shfl_xor(s, m, 64); q2 += __shfl_xor(q2, m, 64); }
    float mean = s * (1.0f / DMODEL);
    float rstd = rsqrtf(fmaxf(q2 * (1.0f / DMODEL) - mean * mean, 0.f) + LN_EPS);
    float4 g = *reinterpret_cast<const float4*>(gp + lane * 4);
    float4 bb = *reinterpret_cast<const float4*>(bp + lane * 4);
    float4 o;
    o.x = (v[0] - mean) * rstd * g.x + bb.x;
    o.y = (v[1] - mean) * rstd * g.y + bb.y;
    o.z = (v[2] - mean) * rstd * g.z + bb.z;
    o.w = (v[3] - mean) * rstd * g.w + bb.w;
    *reinterpret_cast<float4*>(Of + base) = o;
}

// ---------------- 64x64 GEMM (for N=256): 2 blk/CU, dist-2 prefetch ----------------
template<int MODE, bool RELU>
__global__ __launch_bounds__(256) void gemm64(
    const u16* __restrict__ A, const u16* __restrict__ Bt,
    const float* __restrict__ bias, void* __restrict__ Cout,
    int M, int N, int K, int ntn, float osc)
{
    const int lane = threadIdx.x & 63;
    const int wave = threadIdx.x >> 6;
    const int l15 = lane & 15, lhi = lane >> 4;
    const int tn = ((int)blockIdx.x % ntn) * 64;
    const int tm = ((int)blockIdx.x / ntn) * 64;
    const int wm = tm + (wave & 1) * 32;
    const int wn = tn + (wave >> 1) * 32;

    const f32x4 z4 = {0.f, 0.f, 0.f, 0.f};
    f32x4 acc[2][2] = {{z4, z4}, {z4, z4}};

    const u16* a0p = A + (size_t)(wm + l15) * K + lhi * 8;
    const u16* a1p = a0p + (size_t)16 * K;
    const u16* b0p = Bt + (size_t)(wn + l15) * K + lhi * 8;
    const u16* b1p = b0p + (size_t)16 * K;

    bf16x8 aA0 = ldbf8(a0p), aA1 = ldbf8(a1p), bA0 = ldbf8(b0p), bA1 = ldbf8(b1p);
    bf16x8 aB0 = ldbf8(a0p + 32), aB1 = ldbf8(a1p + 32), bB0 = ldbf8(b0p + 32), bB1 = ldbf8(b1p + 32);

#define G64_MFMA(aX0, aX1, bX0, bX1)                                                        \
    acc[0][0] = __builtin_amdgcn_mfma_f32_16x16x32_bf16(aX0, bX0, acc[0][0], 0, 0, 0);      \
    acc[0][1] = __builtin_amdgcn_mfma_f32_16x16x32_bf16(aX0, bX1, acc[0][1], 0, 0, 0);      \
    acc[1][0] = __builtin_amdgcn_mfma_f32_16x16x32_bf16(aX1, bX0, acc[1][0], 0, 0, 0);      \
    acc[1][1] = __builtin_amdgcn_mfma_f32_16x16x32_bf16(aX1, bX1, acc[1][1], 0, 0, 0);

    for (int k = 64; k < K; k += 64) {
        G64_MFMA(aA0, aA1, bA0, bA1);
        aA0 = ldbf8(a0p + k); aA1 = ldbf8(a1p + k);
        bA0 = ldbf8(b0p + k); bA1 = ldbf8(b1p + k);
        G64_MFMA(aB0, aB1, bB0, bB1);
        aB0 = ldbf8(a0p + k + 32); aB1 = ldbf8(a1p + k + 32);
        bB0 = ldbf8(b0p + k + 32); bB1 = ldbf8(b1p + k + 32);
    }
    G64_MFMA(aA0, aA1, bA0, bA1);
    G64_MFMA(aB0, aB1, bB0, bB1);
#undef G64_MFMA

#pragma unroll
    for (int i = 0; i < 2; ++i) {
#pragma unroll
        for (int j = 0; j < 2; ++j) {
            const int col = wn + j * 16 + l15;
            const float bv = bias[col];
            const int row0 = wm + i * 16 + lhi * 4;
            if (MODE == 0) {
                float* C = (float*)Cout;
#pragma unroll
                for (int r = 0; r < 4; ++r) {
                    float v = acc[i][j][r] + bv;
                    if (RELU) v = fmaxf(v, 0.f);
                    C[(size_t)(row0 + r) * N + col] = v;
                }
            } else {
                u16* C = (u16*)Cout;
#pragma unroll
                for (int r = 0; r < 4; ++r) {
                    float v = acc[i][j][r] + bv;
                    if (RELU) v = fmaxf(v, 0.f);
                    C[(size_t)(row0 + r) * N + col] = bfc(v * osc);
                }
            }
        }
    }
}

// ---------------- fused flash attention: 64 q-rows/wave, fixed-base, 2x-unrolled A/B buffers ----------------
__global__ __launch_bounds__(256) void attn_kernel(
    const u16* __restrict__ Qb, const u16* __restrict__ Kb,
    const u16* __restrict__ Vt, const float* __restrict__ mask2,  // pre-scaled by log2e
    u16* __restrict__ Ob, int Sq, int Sk, int MkTot)
{
    const int wave = threadIdx.x >> 6;
    const int lane = threadIdx.x & 63;
    const int l15 = lane & 15, lhi = lane >> 4;
    const int nqc = Sq >> 8;               // 256-row chunks

    // XCD-chunked swizzle (grid % 8 == 0)
    const int nwg = (int)gridDim.x;
    const int p = (int)blockIdx.x;
    const int wgid = (p & 7) * (nwg >> 3) + (p >> 3);

    const int bh = wgid / nqc;
    const int qc = wgid % nqc;
    const int b = bh >> 3;
    const int h = bh & 7;
    const int colh = h * DH;
    const int qrow0 = b * Sq + (qc << 8) + wave * 64;
    const int swz = (l15 & 8) << 1;

    __shared__ __align__(16) u16 pt[4][64][72];   // 36KB

    const f32x4 z4 = {0.f, 0.f, 0.f, 0.f};
    const u16 one_bf = 0x3F80;
    u16x8 ones_u;
#pragma unroll
    for (int i = 0; i < 8; ++i) ones_u[i] = one_bf;
    const bf16x8 ones8 = __builtin_bit_cast(bf16x8, ones_u);

    bf16x8 qf[4];
#pragma unroll
    for (int g = 0; g < 4; ++g)
        qf[g] = ldbf8(Qb + (size_t)(qrow0 + g * 16 + l15) * DMODEL + colh + lhi * 8);

    f32x4 ctx[4][2];
    f32x4 ctxS[4];
#pragma unroll
    for (int g = 0; g < 4; ++g) { ctx[g][0] = z4; ctx[g][1] = z4; ctxS[g] = z4; }

    const float* mb = mask2 + (size_t)b * Sk;
    const u16* kbase = Kb + (size_t)(b * Sk) * DMODEL + colh + lhi * 8;
    const u16* vbase = Vt + (size_t)colh * MkTot + (size_t)b * Sk;

    bf16x8 kfA[4], vfA[4], kfB[4], vfB[4];
    f32x4 mcA[4], mcB[4];

    // prologue: tile 0 -> set A
#pragma unroll
    for (int j = 0; j < 4; ++j)
        kfA[j] = ldbf8(kbase + (size_t)(j * 16 + l15) * DMODEL);
#pragma unroll
    for (int ks = 0; ks < 2; ++ks)
#pragma unroll
        for (int dt = 0; dt < 2; ++dt)
            vfA[ks * 2 + dt] = ldbf8(vbase + (size_t)(dt * 16 + l15) * MkTot + ks * 32 + lhi * 8);
#pragma unroll
    for (int j = 0; j < 4; ++j)
        mcA[j] = *reinterpret_cast<const f32x4*>(mb + j * 16 + lhi * 4);

#define ATTN_STEP(KC, VC, MC, KN, VN, MN, tpre)                                              \
    {                                                                                        \
        f32x4 s[4][4];                                                                       \
        _Pragma("unroll")                                                                    \
        for (int g = 0; g < 4; ++g)                                                          \
            _Pragma("unroll")                                                                \
            for (int j = 0; j < 4; ++j)                                                      \
                s[g][j] = __builtin_amdgcn_mfma_f32_16x16x32_bf16(KC[j], qf[g], MC[j], 0, 0, 0); \
        const int tp = (tpre);                                                               \
        _Pragma("unroll")                                                                    \
        for (int j = 0; j < 4; ++j)                                                          \
            KN[j] = ldbf8(kbase + (size_t)(tp + j * 16 + l15) * DMODEL);                     \
        _Pragma("unroll")                                                                    \
        for (int ks = 0; ks < 2; ++ks)                                                       \
            _Pragma("unroll")                                                                \
            for (int dt = 0; dt < 2; ++dt)                                                   \
                VN[ks * 2 + dt] = ldbf8(vbase + (size_t)(dt * 16 + l15) * MkTot + tp + ks * 32 + lhi * 8); \
        _Pragma("unroll")                                                                    \
        for (int j = 0; j < 4; ++j)                                                          \
            MN[j] = *reinterpret_cast<const f32x4*>(mb + tp + j * 16 + lhi * 4);             \
        _Pragma("unroll")                                                                    \
        for (int g = 0; g < 4; ++g)                                                          \
            _Pragma("unroll")                                                                \
            for (int j = 0; j < 4; ++j) {                                                    \
                s[g][j][0] = EXP2(s[g][j][0]);                                               \
                s[g][j][1] = EXP2(s[g][j][1]);                                               \
                s[g][j][2] = EXP2(s[g][j][2]);                                               \
                s[g][j][3] = EXP2(s[g][j][3]);                                               \
            }                                                                                \
        asm volatile("" ::: "memory");                                                       \
        _Pragma("unroll")                                                                    \
        for (int g = 0; g < 4; ++g)                                                          \
            _Pragma("unroll")                                                                \
            for (int j = 0; j < 4; ++j) {                                                    \
                ushort4 w = make_ushort4(bfc(s[g][j][0]), bfc(s[g][j][1]),                   \
                                         bfc(s[g][j][2]), bfc(s[g][j][3]));                  \
                *reinterpret_cast<ushort4*>(&pt[wave][g * 16 + l15][(j * 16 + lhi * 4) ^ swz]) = w; \
            }                                                                                \
        asm volatile("" ::: "memory");                                                       \
        _Pragma("unroll")                                                                    \
        for (int ks = 0; ks < 2; ++ks) {                                                     \
            bf16x8 pa[4];                                                                    \
            _Pragma("unroll")                                                                \
            for (int g = 0; g < 4; ++g)                                                      \
                pa[g] = ldbf8(&pt[wave][g * 16 + l15][(ks * 32 + lhi * 8) ^ swz]);           \
            _Pragma("unroll")                                                                \
            for (int g = 0; g < 4; ++g) {                                                    \
                _Pragma("unroll")                                                            \
                for (int dt = 0; dt < 2; ++dt)                                               \
                    ctx[g][dt] = __builtin_amdgcn_mfma_f32_16x16x32_bf16(pa[g], VC[ks * 2 + dt], ctx[g][dt], 0, 0, 0); \
                ctxS[g] = __builtin_amdgcn_mfma_f32_16x16x32_bf16(pa[g], ones8, ctxS[g], 0, 0, 0); \
            }                                                                                \
        }                                                                                    \
    }

    const int NT = Sk >> 6;   // SA: 32, CA: 16 (even)
    for (int t = 0; t < NT; t += 2) {
        const int t1 = (t + 1) << 6;
        ATTN_STEP(kfA, vfA, mcA, kfB, vfB, mcB, t1);
        const int t2 = ((t + 2 < NT) ? t + 2 : t + 1) << 6;
        ATTN_STEP(kfB, vfB, mcB, kfA, vfA, mcA, t2);
    }
#undef ATTN_STEP

    // ---- epilogue ----
#pragma unroll
    for (int g = 0; g < 4; ++g)
#pragma unroll
        for (int r = 0; r < 4; ++r) {
            const float inv = 1.0f / ctxS[g][r];
            const int row = qrow0 + g * 16 + lhi * 4 + r;
#pragma unroll
            for (int dt = 0; dt < 2; ++dt)
                Ob[(size_t)row * DMODEL + colh + dt * 16 + l15] = bfc(ctx[g][dt][r] * inv);
        }
}

// ---------------- LayerNorm (fused residual add; optional 2nd LN) ----------------
template<bool DBL, bool WBF>
__global__ __launch_bounds__(256) void ln_kernel(
    const float* __restrict__ X, const float* __restrict__ Res,
    const float* __restrict__ g1p, const float* __restrict__ b1p,
    const float* __restrict__ g2p, const float* __restrict__ b2p,
    float* __restrict__ Of, u16* __restrict__ Oh)
{
    const int lane = threadIdx.x & 63;
    const int row = blockIdx.x * 4 + (threadIdx.x >> 6);
    const size_t base = (size_t)row * DMODEL + lane * 4;
    float4 x = *reinterpret_cast<const float4*>(X + base);
    float4 rr = *reinterpret_cast<const float4*>(Res + base);
    float v[4] = {x.x + rr.x, x.y + rr.y, x.z + rr.z, x.w + rr.w};
    float s = v[0] + v[1] + v[2] + v[3];
    float q = v[0] * v[0] + v[1] * v[1] + v[2] * v[2] + v[3] * v[3];
#pragma unroll
    for (int m = 1; m < 64; m <<= 1) { s += __shfl_xor(s, m, 64); q += __shfl_xor(q, m, 64); }
    float mean = s * (1.0f / DMODEL);
    float rstd = rsqrtf(fmaxf(q * (1.0f / DMODEL) - mean * mean, 0.f) + LN_EPS);
    float4 g = *reinterpret_cast<const float4*>(g1p + lane * 4);
    float4 bb = *reinterpret_cast<const float4*>(b1p + lane * 4);
    float y[4];
    y[0] = (v[0] - mean) * rstd * g.x + bb.x;
    y[1] = (v[1] - mean) * rstd * g.y + bb.y;
    y[2] = (v[2] - mean) * rstd * g.z + bb.z;
    y[3] = (v[3] - mean) * rstd * g.w + bb.w;
    if constexpr (DBL) {
#pragma unroll
        for (int k2 = 0; k2 < 4; ++k2) y[k2] *= 2.0f;
        float s2 = y[0] + y[1] + y[2] + y[3];
        float q2 = y[0] * y[0] + y[1] * y[1] + y[2] * y[2] + y[3] * y[3];
#pragma unroll
        for (int m = 1; m < 64; m <<= 1) { s2 += __shfl_xor(s2, m, 64); q2 += __shfl_xor(q2, m, 64); }
        float mean2 = s2 * (1.0f / DMODEL);
        float rstd2 = rsqrtf(fmaxf(q2 * (1.0f / DMODEL) - mean2 * mean2, 0.f) + LN_EPS);
        float4 g2 = *reinterpret_cast<const float4*>(g2p + lane * 4);
        float4 b2 = *reinterpret_cast<const float4*>(b2p + lane * 4);
        y[0] = (y[0] - mean2) * rstd2 * g2.x + b2.x;
        y[1] = (y[1] - mean2) * rstd2 * g2.y + b2.y;
        y[2] = (y[2] - mean2) * rstd2 * g2.z + b2.z;
        y[3] = (y[3] - mean2) * rstd2 * g2.w + b2.w;
    }
    *reinterpret_cast<float4*>(Of + base) = make_float4(y[0], y[1], y[2], y[3]);
    if constexpr (WBF) {
        ushort4 o = make_ushort4(bfc(y[0]), bfc(y[1]), bfc(y[2]), bfc(y[3]));
        *reinterpret_cast<ushort4*>(Oh + base) = o;
    }
}

// ---------------- host-side orchestration ----------------
extern "C" void kernel_launch(void* const* d_in, const int* in_sizes, int n_in,
                              void* d_out, int out_size, void* d_ws, size_t ws_size,
                              hipStream_t stream) {
    constexpr size_t MB = 1u << 20;
    if (ws_size < 70 * MB) return;

    const float* vis   = (const float*)d_in[0];
    const float* txt   = (const float*)d_in[1];
    const float* vmask = (const float*)d_in[2];
    const float* tmask = (const float*)d_in[3];
    const float* sa_wq = (const float*)d_in[4];  const float* sa_bq = (const float*)d_in[5];
    const float* sa_wk = (const float*)d_in[6];  const float* sa_bk = (const float*)d_in[7];
    const float* sa_wv = (const float*)d_in[8];  const float* sa_bv = (const float*)d_in[9];
    const float* sa_wo = (const float*)d_in[10]; const float* sa_bo = (const float*)d_in[11];
    const float* ca_wq = (const float*)d_in[12]; const float* ca_bq = (const float*)d_in[13];
    const float* ca_wk = (const float*)d_in[14]; const float* ca_bk = (const float*)d_in[15];
    const float* ca_wv = (const float*)d_in[16]; const float* ca_bv = (const float*)d_in[17];
    const float* ca_wo = (const float*)d_in[18]; const float* ca_bo = (const float*)d_in[19];
    const float* ln1_g = (const float*)d_in[20]; const float* ln1_b = (const float*)d_in[21];
    const float* ln2_g = (const float*)d_in[22]; const float* ln2_b = (const float*)d_in[23];
    const float* ln3_g = (const float*)d_in[24]; const float* ln3_b = (const float*)d_in[25];
    const float* ln4_g = (const float*)d_in[26]; const float* ln4_b = (const float*)d_in[27];
    const float* fc1_w = (const float*)d_in[28]; const float* fc1_b = (const float*)d_in[29];
    const float* fc2_w = (const float*)d_in[30]; const float* fc2_b = (const float*)d_in[31];

    const int B = 4, Sq = 2048, St = 1024;
    const int Mq = B * Sq;   // 8192
    const int Mt = B * St;   // 4096

    char* ws = (char*)d_ws;
    u16*   q_bf    = (u16*)(ws + 6 * MB);
    u16*   k_bf    = (u16*)(ws + 10 * MB);
    u16*   vt_bf   = (u16*)(ws + 14 * MB);
    u16*   ctx_bf  = (u16*)(ws + 18 * MB);
    u16*   ffn1_bf = (u16*)(ws + 0);          // 32MB, overlaps (dead by FFN)
    float* attn_f  = (float*)(ws + 32 * MB);
    float* h1_f    = (float*)(ws + 40 * MB);
    u16*   h1_bf   = (u16*)(ws + 48 * MB);
    float* h3_f    = (float*)(ws + 52 * MB);
    u16*   h3_bf   = (u16*)(ws + 60 * MB);
    u16*   wts     = (u16*)(ws + 64 * MB);
    u16*   ffn2p   = (u16*)(ws + 32 * MB);    // 16MB: 4 bf16 partials (attn_f/h1_f dead by FFN2)

    u16* wqkv_t = wts;                        // [768][256]
    u16* wkv_t  = wqkv_t + 768 * 256;         // [512][256]
    u16* cwq_t  = wkv_t + 512 * 256;
    u16* wo_t   = cwq_t + 65536;
    u16* cwo_t  = wo_t + 65536;
    u16* fc1_t  = cwo_t + 65536;              // [2048][256]
    u16* fc2_t  = fc1_t + 2048 * 256;         // [256][2048]
    float* vmask2 = (float*)(ws + 68 * MB);   // [4][2048] pre-scaled
    float* tmask2 = vmask2 + B * Sq;          // [4][1024]

    scale_mask<<<dim3((B * Sq + 255) / 256), 256, 0, stream>>>(vmask, vmask2, B * Sq);
    scale_mask<<<dim3((B * St + 255) / 256), 256, 0, stream>>>(tmask, tmask2, B * St);

    TArgs ta;
    ta.d[0] = {sa_wq, wqkv_t + 0 * 65536, 256, 256};
    ta.d[1] = {sa_wk, wqkv_t + 1 * 65536, 256, 256};
    ta.d[2] = {sa_wv, wqkv_t + 2 * 65536, 256, 256};
    ta.d[3] = {ca_wk, wkv_t + 0 * 65536, 256, 256};
    ta.d[4] = {ca_wv, wkv_t + 1 * 65536, 256, 256};
    ta.d[5] = {ca_wq, cwq_t, 256, 256};
    ta.d[6] = {sa_wo, wo_t, 256, 256};
    ta.d[7] = {ca_wo, cwo_t, 256, 256};
    ta.d[8] = {fc1_w, fc1_t, 256, 2048};
    ta.d[9] = {fc2_w, fc2_t, 2048, 256};
    transpose_cvt<<<dim3(512, 10), 256, 0, stream>>>(ta);

    // self-attention
    Slice sq = {q_bf, sa_bq, 1, QSCALE2}, sk = {k_bf, sa_bk, 1, 1.f}, sv = {vt_bf, sa_bv, 2, 1.f};
    gemm_xproj<<<dim3((Mq / 128) * 12), 256, 0, stream>>>(vis, wqkv_t, sq, sk, sv, Mq, Mq / 128);
    attn_kernel<<<dim3(B * HEADS * (Sq / 256)), 256, 0, stream>>>(q_bf, k_bf, vt_bf, vmask2, ctx_bf, Sq, Sq, Mq);
    gemm64<0, false><<<dim3((Mq / 64) * 4), 256, 0, stream>>>(ctx_bf, wo_t, sa_bo, attn_f, Mq, 256, 256, 4, 1.f);
    ln_kernel<false, true><<<dim3(Mq / 4), 256, 0, stream>>>(attn_f, vis, ln1_g, ln1_b, nullptr, nullptr, h1_f, h1_bf);

    // cross-attention
    Slice ck = {k_bf, ca_bk, 1, 1.f}, cv = {vt_bf, ca_bv, 2, 1.f}, cd = {nullptr, nullptr, 1, 1.f};
    gemm_xproj<<<dim3((Mt / 128) * 8), 256, 0, stream>>>(txt, wkv_t, ck, cv, cd, Mt, Mt / 128);
    gemm64<1, false><<<dim3((Mq / 64) * 4), 256, 0, stream>>>(h1_bf, cwq_t, ca_bq, q_bf, Mq, 256, 256, 4, QSCALE2);
    attn_kernel<<<dim3(B * HEADS * (Sq / 256)), 256, 0, stream>>>(q_bf, k_bf, vt_bf, tmask2, ctx_bf, Sq, St, Mt);
    gemm64<0, false><<<dim3((Mq / 64) * 4), 256, 0, stream>>>(ctx_bf, cwo_t, ca_bo, attn_f, Mq, 256, 256, 4, 1.f);
    ln_kernel<true, true><<<dim3(Mq / 4), 256, 0, stream>>>(attn_f, h1_f, ln2_g, ln2_b, ln3_g, ln3_b, h3_f, h3_bf);

    // FFN: wide GEMM for FC1, split-K4 (128x64, dist-2, 4 blk/CU) for FC2, ln_sum4 finishes
    gemm_wide<1, true><<<dim3((Mq / 128) * 16), 256, 0, stream>>>(h3_bf, fc1_t, fc1_b, ffn1_bf, Mq, 2048, 256, Mq / 128, 1.f);
    gemm_sk4<<<dim3((Mq / 128) * 4 * 4), 256, 0, stream>>>(ffn1_bf, fc2_t, fc2_b, ffn2p, Mq, 256, 2048, 512, Mq / 128);
    ln_sum4<<<dim3(Mq / 4), 256, 0, stream>>>(ffn2p, h3_f, ln4_g, ln4_b, (float*)d_out, Mq * 256);
}

// Round 22
// 245.880 us; speedup vs baseline: 1.0075x; 1.0075x over previous
//
#include <hip/hip_runtime.h>
#include <stdint.h>
#include <stddef.h>

#define HEADS 8
#define DH 32
#define DMODEL 256
#define LN_EPS 1e-5f
#define LOG2E 1.4426950408889634f
#define QSCALE 0.17677669529663687f       // 1/sqrt(32)
#define QSCALE2 (QSCALE * LOG2E)          // folded: exp2 domain
#define EXP2(x) __builtin_amdgcn_exp2f(x) // v_exp_f32 (base-2 native)

typedef unsigned short u16;
typedef __bf16 bf16x8 __attribute__((ext_vector_type(8)));
typedef unsigned short u16x8 __attribute__((ext_vector_type(8)));
typedef float f32x4 __attribute__((ext_vector_type(4)));

static __device__ __forceinline__ u16 bfc(float f) {          // hw cvt (RNE)
    return __builtin_bit_cast(u16, (__bf16)f);
}
static __device__ __forceinline__ bf16x8 ldbf8(const u16* p) {
    return __builtin_bit_cast(bf16x8, *reinterpret_cast<const u16x8*>(p));
}
static __device__ __forceinline__ bf16x8 cvt8(float4 a, float4 b) {
    bf16x8 r;
    r[0] = (__bf16)a.x; r[1] = (__bf16)a.y; r[2] = (__bf16)a.z; r[3] = (__bf16)a.w;
    r[4] = (__bf16)b.x; r[5] = (__bf16)b.y; r[6] = (__bf16)b.z; r[7] = (__bf16)b.w;
    return r;
}

// ---------------- mask pre-scale: out = in * log2e ----------------
__global__ __launch_bounds__(256) void scale_mask(const float* __restrict__ in,
                                                  float* __restrict__ out, int n) {
    int i = blockIdx.x * 256 + threadIdx.x;
    if (i < n) out[i] = in[i] * LOG2E;
}

// ---------------- batched transpose + convert: W[K][N] -> Wt[N][K] bf16 ----------------
struct TDesc { const float* src; u16* dst; int K; int N; };
struct TArgs { TDesc d[10]; };

__global__ __launch_bounds__(256) void transpose_cvt(TArgs args) {
    TDesc d = args.d[blockIdx.y];
    const int ntx = d.N >> 5;
    const int tiles = (d.K >> 5) * ntx;
    if ((int)blockIdx.x >= tiles) return;
    const int tk = (blockIdx.x / ntx) << 5;
    const int tn = (blockIdx.x % ntx) << 5;
    __shared__ float t[32][33];
    const int lx = threadIdx.x & 31;
    const int ly = threadIdx.x >> 5;
#pragma unroll
    for (int i = 0; i < 4; ++i)
        t[ly + 8 * i][lx] = d.src[(size_t)(tk + ly + 8 * i) * d.N + tn + lx];
    __syncthreads();
#pragma unroll
    for (int i = 0; i < 4; ++i)
        d.dst[(size_t)(tn + ly + 8 * i) * d.K + tk + lx] = bfc(t[lx][ly + 8 * i]);
}

// ---------------- fused projection GEMM: f32 A -> up to 3 output slices (m-fastest) ----------------
struct Slice { u16* out; const float* bias; int mode; float sc; };

__global__ __launch_bounds__(256) void gemm_xproj(
    const float* __restrict__ Af, const u16* __restrict__ Wt,
    Slice s0, Slice s1, Slice s2, int M, int ntm)
{
    const int lane = threadIdx.x & 63;
    const int wave = threadIdx.x >> 6;
    const int l15 = lane & 15, lhi = lane >> 4;
    const int tm = ((int)blockIdx.x % ntm) * 128;
    const int tn = ((int)blockIdx.x / ntm) * 64;
    const int wm = tm + wave * 32;
    const int sel = tn >> 8;
    const int tl = tn & 255;
    Slice sl = (sel == 0) ? s0 : (sel == 1 ? s1 : s2);

    const f32x4 z4 = {0.f, 0.f, 0.f, 0.f};
    f32x4 acc[2][4];
#pragma unroll
    for (int i = 0; i < 2; ++i)
#pragma unroll
        for (int j = 0; j < 4; ++j) acc[i][j] = z4;

    const float* ar0 = Af + (size_t)(wm + l15) * 256 + lhi * 8;
    const float* ar1 = ar0 + (size_t)16 * 256;
    const u16* b0p = Wt + (size_t)(tn + l15) * 256 + lhi * 8;

    float4 a00 = *(const float4*)(ar0), a01 = *(const float4*)(ar0 + 4);
    float4 a10 = *(const float4*)(ar1), a11 = *(const float4*)(ar1 + 4);
    bf16x8 b[4];
#pragma unroll
    for (int j = 0; j < 4; ++j) b[j] = ldbf8(b0p + (size_t)j * 16 * 256);

#pragma unroll
    for (int k = 32; k < 256; k += 32) {
        float4 n00 = *(const float4*)(ar0 + k), n01 = *(const float4*)(ar0 + k + 4);
        float4 n10 = *(const float4*)(ar1 + k), n11 = *(const float4*)(ar1 + k + 4);
        bf16x8 bn[4];
#pragma unroll
        for (int j = 0; j < 4; ++j) bn[j] = ldbf8(b0p + (size_t)j * 16 * 256 + k);
        bf16x8 a0 = cvt8(a00, a01), a1 = cvt8(a10, a11);
#pragma unroll
        for (int j = 0; j < 4; ++j) {
            acc[0][j] = __builtin_amdgcn_mfma_f32_16x16x32_bf16(a0, b[j], acc[0][j], 0, 0, 0);
            acc[1][j] = __builtin_amdgcn_mfma_f32_16x16x32_bf16(a1, b[j], acc[1][j], 0, 0, 0);
        }
        a00 = n00; a01 = n01; a10 = n10; a11 = n11;
#pragma unroll
        for (int j = 0; j < 4; ++j) b[j] = bn[j];
    }
    {
        bf16x8 a0 = cvt8(a00, a01), a1 = cvt8(a10, a11);
#pragma unroll
        for (int j = 0; j < 4; ++j) {
            acc[0][j] = __builtin_amdgcn_mfma_f32_16x16x32_bf16(a0, b[j], acc[0][j], 0, 0, 0);
            acc[1][j] = __builtin_amdgcn_mfma_f32_16x16x32_bf16(a1, b[j], acc[1][j], 0, 0, 0);
        }
    }

#pragma unroll
    for (int i = 0; i < 2; ++i) {
#pragma unroll
        for (int j = 0; j < 4; ++j) {
            const int col = tl + j * 16 + l15;
            const float bv = sl.bias[col];
            const int row0 = wm + i * 16 + lhi * 4;
            if (sl.mode == 1) {
#pragma unroll
                for (int r = 0; r < 4; ++r)
                    sl.out[(size_t)(row0 + r) * 256 + col] = bfc((acc[i][j][r] + bv) * sl.sc);
            } else {
                ushort4 o = make_ushort4(bfc((acc[i][j][0] + bv) * sl.sc), bfc((acc[i][j][1] + bv) * sl.sc),
                                         bfc((acc[i][j][2] + bv) * sl.sc), bfc((acc[i][j][3] + bv) * sl.sc));
                *reinterpret_cast<ushort4*>(sl.out + (size_t)col * M + row0) = o;
            }
        }
    }
}

// ---------------- WIDE GEMM: 128x128 tile, wave = 32x128 (16 MFMA : 10 loads) ----------------
template<int MODE, bool RELU>
__global__ __launch_bounds__(256) void gemm_wide(
    const u16* __restrict__ A, const u16* __restrict__ Bt,
    const float* __restrict__ bias, void* __restrict__ Cout,
    int M, int N, int K, int ntm, float osc)
{
    const int lane = threadIdx.x & 63;
    const int wave = threadIdx.x >> 6;
    const int l15 = lane & 15, lhi = lane >> 4;
    const int tm = ((int)blockIdx.x % ntm) * 128;
    const int tn = ((int)blockIdx.x / ntm) * 128;
    const int wm = tm + wave * 32;

    const f32x4 z4 = {0.f, 0.f, 0.f, 0.f};
    f32x4 acc[2][8];
#pragma unroll
    for (int i = 0; i < 2; ++i)
#pragma unroll
        for (int j = 0; j < 8; ++j) acc[i][j] = z4;

    const u16* a0p = A + (size_t)(wm + l15) * K + lhi * 8;
    const u16* a1p = a0p + (size_t)16 * K;
    const u16* b0p = Bt + (size_t)(tn + l15) * K + lhi * 8;

    bf16x8 a0 = ldbf8(a0p), a1 = ldbf8(a1p);
    bf16x8 b[8];
#pragma unroll
    for (int j = 0; j < 8; ++j) b[j] = ldbf8(b0p + (size_t)j * 16 * K);

    for (int k = 32; k < K; k += 32) {
        bf16x8 a0n = ldbf8(a0p + k), a1n = ldbf8(a1p + k);
        bf16x8 bn[8];
#pragma unroll
        for (int j = 0; j < 8; ++j) bn[j] = ldbf8(b0p + (size_t)j * 16 * K + k);
#pragma unroll
        for (int j = 0; j < 8; ++j) {
            acc[0][j] = __builtin_amdgcn_mfma_f32_16x16x32_bf16(a0, b[j], acc[0][j], 0, 0, 0);
            acc[1][j] = __builtin_amdgcn_mfma_f32_16x16x32_bf16(a1, b[j], acc[1][j], 0, 0, 0);
        }
        a0 = a0n; a1 = a1n;
#pragma unroll
        for (int j = 0; j < 8; ++j) b[j] = bn[j];
    }
#pragma unroll
    for (int j = 0; j < 8; ++j) {
        acc[0][j] = __builtin_amdgcn_mfma_f32_16x16x32_bf16(a0, b[j], acc[0][j], 0, 0, 0);
        acc[1][j] = __builtin_amdgcn_mfma_f32_16x16x32_bf16(a1, b[j], acc[1][j], 0, 0, 0);
    }

#pragma unroll
    for (int i = 0; i < 2; ++i) {
#pragma unroll
        for (int j = 0; j < 8; ++j) {
            const int col = tn + j * 16 + l15;
            const float bv = bias[col];
            const int row0 = wm + i * 16 + lhi * 4;
            if (MODE == 0) {
                float* C = (float*)Cout;
#pragma unroll
                for (int r = 0; r < 4; ++r) {
                    float v = acc[i][j][r] + bv;
                    if (RELU) v = fmaxf(v, 0.f);
                    C[(size_t)(row0 + r) * N + col] = v;
                }
            } else {
                u16* C = (u16*)Cout;
#pragma unroll
                for (int r = 0; r < 4; ++r) {
                    float v = acc[i][j][r] + bv;
                    if (RELU) v = fmaxf(v, 0.f);
                    C[(size_t)(row0 + r) * N + col] = bfc(v * osc);
                }
            }
        }
    }
}

// ---------------- split-K2 GEMM (FFN2): 128x64 tile, dist-2 prefetch, 512 blocks ----------------
// blocks [0,half): K[0:Kh] + bias -> C; blocks [half,2*half): K[Kh:2Kh], no bias -> C + M*N.
__global__ __launch_bounds__(256) void gemm_sk2(
    const u16* __restrict__ A, const u16* __restrict__ Bt,
    const float* __restrict__ bias, float* __restrict__ Cout,
    int M, int N, int lda, int Kh, int ntm)
{
    const int half = ntm * (N / 64);
    const int kh = (int)blockIdx.x >= half;
    const int bid = (int)blockIdx.x - kh * half;
    const int lane = threadIdx.x & 63;
    const int wave = threadIdx.x >> 6;
    const int l15 = lane & 15, lhi = lane >> 4;
    const int tm = (bid % ntm) * 128;
    const int tn = (bid / ntm) * 64;
    const int wm = tm + wave * 32;

    const f32x4 z4 = {0.f, 0.f, 0.f, 0.f};
    f32x4 acc[2][4];
#pragma unroll
    for (int i = 0; i < 2; ++i)
#pragma unroll
        for (int j = 0; j < 4; ++j) acc[i][j] = z4;

    const u16* a0p = A + (size_t)(wm + l15) * lda + kh * Kh + lhi * 8;
    const u16* a1p = a0p + (size_t)16 * lda;
    const u16* b0p = Bt + (size_t)(tn + l15) * lda + kh * Kh + lhi * 8;

    // distance-2: two named load sets over a 64-K unroll (keeps 8-acc ILP of 128x64)
    bf16x8 aA0 = ldbf8(a0p), aA1 = ldbf8(a1p);
    bf16x8 bA[4];
#pragma unroll
    for (int j = 0; j < 4; ++j) bA[j] = ldbf8(b0p + (size_t)j * 16 * lda);
    bf16x8 aB0 = ldbf8(a0p + 32), aB1 = ldbf8(a1p + 32);
    bf16x8 bB[4];
#pragma unroll
    for (int j = 0; j < 4; ++j) bB[j] = ldbf8(b0p + (size_t)j * 16 * lda + 32);

    for (int k = 64; k < Kh; k += 64) {
#pragma unroll
        for (int j = 0; j < 4; ++j) {
            acc[0][j] = __builtin_amdgcn_mfma_f32_16x16x32_bf16(aA0, bA[j], acc[0][j], 0, 0, 0);
            acc[1][j] = __builtin_amdgcn_mfma_f32_16x16x32_bf16(aA1, bA[j], acc[1][j], 0, 0, 0);
        }
        aA0 = ldbf8(a0p + k); aA1 = ldbf8(a1p + k);
#pragma unroll
        for (int j = 0; j < 4; ++j) bA[j] = ldbf8(b0p + (size_t)j * 16 * lda + k);
#pragma unroll
        for (int j = 0; j < 4; ++j) {
            acc[0][j] = __builtin_amdgcn_mfma_f32_16x16x32_bf16(aB0, bB[j], acc[0][j], 0, 0, 0);
            acc[1][j] = __builtin_amdgcn_mfma_f32_16x16x32_bf16(aB1, bB[j], acc[1][j], 0, 0, 0);
        }
        aB0 = ldbf8(a0p + k + 32); aB1 = ldbf8(a1p + k + 32);
#pragma unroll
        for (int j = 0; j < 4; ++j) bB[j] = ldbf8(b0p + (size_t)j * 16 * lda + k + 32);
    }
#pragma unroll
    for (int j = 0; j < 4; ++j) {
        acc[0][j] = __builtin_amdgcn_mfma_f32_16x16x32_bf16(aA0, bA[j], acc[0][j], 0, 0, 0);
        acc[1][j] = __builtin_amdgcn_mfma_f32_16x16x32_bf16(aA1, bA[j], acc[1][j], 0, 0, 0);
    }
#pragma unroll
    for (int j = 0; j < 4; ++j) {
        acc[0][j] = __builtin_amdgcn_mfma_f32_16x16x32_bf16(aB0, bB[j], acc[0][j], 0, 0, 0);
        acc[1][j] = __builtin_amdgcn_mfma_f32_16x16x32_bf16(aB1, bB[j], acc[1][j], 0, 0, 0);
    }

    float* C = Cout + (size_t)kh * M * N;
    const float bs = kh ? 0.f : 1.f;
#pragma unroll
    for (int i = 0; i < 2; ++i) {
#pragma unroll
        for (int j = 0; j < 4; ++j) {
            const int col = tn + j * 16 + l15;
            const float bv = bias[col] * bs;
            const int row0 = wm + i * 16 + lhi * 4;
#pragma unroll
            for (int r = 0; r < 4; ++r)
                C[(size_t)(row0 + r) * N + col] = acc[i][j][r] + bv;
        }
    }
}

// ---------------- 64x64 GEMM (for N=256): 2 blk/CU, dist-2 prefetch ----------------
template<int MODE, bool RELU>
__global__ __launch_bounds__(256) void gemm64(
    const u16* __restrict__ A, const u16* __restrict__ Bt,
    const float* __restrict__ bias, void* __restrict__ Cout,
    int M, int N, int K, int ntn, float osc)
{
    const int lane = threadIdx.x & 63;
    const int wave = threadIdx.x >> 6;
    const int l15 = lane & 15, lhi = lane >> 4;
    const int tn = ((int)blockIdx.x % ntn) * 64;
    const int tm = ((int)blockIdx.x / ntn) * 64;
    const int wm = tm + (wave & 1) * 32;
    const int wn = tn + (wave >> 1) * 32;

    const f32x4 z4 = {0.f, 0.f, 0.f, 0.f};
    f32x4 acc[2][2] = {{z4, z4}, {z4, z4}};

    const u16* a0p = A + (size_t)(wm + l15) * K + lhi * 8;
    const u16* a1p = a0p + (size_t)16 * K;
    const u16* b0p = Bt + (size_t)(wn + l15) * K + lhi * 8;
    const u16* b1p = b0p + (size_t)16 * K;

    bf16x8 aA0 = ldbf8(a0p), aA1 = ldbf8(a1p), bA0 = ldbf8(b0p), bA1 = ldbf8(b1p);
    bf16x8 aB0 = ldbf8(a0p + 32), aB1 = ldbf8(a1p + 32), bB0 = ldbf8(b0p + 32), bB1 = ldbf8(b1p + 32);

#define G64_MFMA(aX0, aX1, bX0, bX1)                                                        \
    acc[0][0] = __builtin_amdgcn_mfma_f32_16x16x32_bf16(aX0, bX0, acc[0][0], 0, 0, 0);      \
    acc[0][1] = __builtin_amdgcn_mfma_f32_16x16x32_bf16(aX0, bX1, acc[0][1], 0, 0, 0);      \
    acc[1][0] = __builtin_amdgcn_mfma_f32_16x16x32_bf16(aX1, bX0, acc[1][0], 0, 0, 0);      \
    acc[1][1] = __builtin_amdgcn_mfma_f32_16x16x32_bf16(aX1, bX1, acc[1][1], 0, 0, 0);

    for (int k = 64; k < K; k += 64) {
        G64_MFMA(aA0, aA1, bA0, bA1);
        aA0 = ldbf8(a0p + k); aA1 = ldbf8(a1p + k);
        bA0 = ldbf8(b0p + k); bA1 = ldbf8(b1p + k);
        G64_MFMA(aB0, aB1, bB0, bB1);
        aB0 = ldbf8(a0p + k + 32); aB1 = ldbf8(a1p + k + 32);
        bB0 = ldbf8(b0p + k + 32); bB1 = ldbf8(b1p + k + 32);
    }
    G64_MFMA(aA0, aA1, bA0, bA1);
    G64_MFMA(aB0, aB1, bB0, bB1);
#undef G64_MFMA

#pragma unroll
    for (int i = 0; i < 2; ++i) {
#pragma unroll
        for (int j = 0; j < 2; ++j) {
            const int col = wn + j * 16 + l15;
            const float bv = bias[col];
            const int row0 = wm + i * 16 + lhi * 4;
            if (MODE == 0) {
                float* C = (float*)Cout;
#pragma unroll
                for (int r = 0; r < 4; ++r) {
                    float v = acc[i][j][r] + bv;
                    if (RELU) v = fmaxf(v, 0.f);
                    C[(size_t)(row0 + r) * N + col] = v;
                }
            } else {
                u16* C = (u16*)Cout;
#pragma unroll
                for (int r = 0; r < 4; ++r) {
                    float v = acc[i][j][r] + bv;
                    if (RELU) v = fmaxf(v, 0.f);
                    C[(size_t)(row0 + r) * N + col] = bfc(v * osc);
                }
            }
        }
    }
}

// ---------------- fused flash attention: 64 q-rows/wave, fixed-base, 2x-unrolled A/B buffers ----------------
__global__ __launch_bounds__(256) void attn_kernel(
    const u16* __restrict__ Qb, const u16* __restrict__ Kb,
    const u16* __restrict__ Vt, const float* __restrict__ mask2,  // pre-scaled by log2e
    u16* __restrict__ Ob, int Sq, int Sk, int MkTot)
{
    const int wave = threadIdx.x >> 6;
    const int lane = threadIdx.x & 63;
    const int l15 = lane & 15, lhi = lane >> 4;
    const int nqc = Sq >> 8;               // 256-row chunks

    // XCD-chunked swizzle (grid % 8 == 0)
    const int nwg = (int)gridDim.x;
    const int p = (int)blockIdx.x;
    const int wgid = (p & 7) * (nwg >> 3) + (p >> 3);

    const int bh = wgid / nqc;
    const int qc = wgid % nqc;
    const int b = bh >> 3;
    const int h = bh & 7;
    const int colh = h * DH;
    const int qrow0 = b * Sq + (qc << 8) + wave * 64;
    const int swz = (l15 & 8) << 1;

    __shared__ __align__(16) u16 pt[4][64][72];   // 36KB

    const f32x4 z4 = {0.f, 0.f, 0.f, 0.f};
    const u16 one_bf = 0x3F80;
    u16x8 ones_u;
#pragma unroll
    for (int i = 0; i < 8; ++i) ones_u[i] = one_bf;
    const bf16x8 ones8 = __builtin_bit_cast(bf16x8, ones_u);

    bf16x8 qf[4];
#pragma unroll
    for (int g = 0; g < 4; ++g)
        qf[g] = ldbf8(Qb + (size_t)(qrow0 + g * 16 + l15) * DMODEL + colh + lhi * 8);

    f32x4 ctx[4][2];
    f32x4 ctxS[4];
#pragma unroll
    for (int g = 0; g < 4; ++g) { ctx[g][0] = z4; ctx[g][1] = z4; ctxS[g] = z4; }

    const float* mb = mask2 + (size_t)b * Sk;
    const u16* kbase = Kb + (size_t)(b * Sk) * DMODEL + colh + lhi * 8;
    const u16* vbase = Vt + (size_t)colh * MkTot + (size_t)b * Sk;

    bf16x8 kfA[4], vfA[4], kfB[4], vfB[4];
    f32x4 mcA[4], mcB[4];

    // prologue: tile 0 -> set A
#pragma unroll
    for (int j = 0; j < 4; ++j)
        kfA[j] = ldbf8(kbase + (size_t)(j * 16 + l15) * DMODEL);
#pragma unroll
    for (int ks = 0; ks < 2; ++ks)
#pragma unroll
        for (int dt = 0; dt < 2; ++dt)
            vfA[ks * 2 + dt] = ldbf8(vbase + (size_t)(dt * 16 + l15) * MkTot + ks * 32 + lhi * 8);
#pragma unroll
    for (int j = 0; j < 4; ++j)
        mcA[j] = *reinterpret_cast<const f32x4*>(mb + j * 16 + lhi * 4);

#define ATTN_STEP(KC, VC, MC, KN, VN, MN, tpre)                                              \
    {                                                                                        \
        f32x4 s[4][4];                                                                       \
        _Pragma("unroll")                                                                    \
        for (int g = 0; g < 4; ++g)                                                          \
            _Pragma("unroll")                                                                \
            for (int j = 0; j < 4; ++j)                                                      \
                s[g][j] = __builtin_amdgcn_mfma_f32_16x16x32_bf16(KC[j], qf[g], MC[j], 0, 0, 0); \
        const int tp = (tpre);                                                               \
        _Pragma("unroll")                                                                    \
        for (int j = 0; j < 4; ++j)                                                          \
            KN[j] = ldbf8(kbase + (size_t)(tp + j * 16 + l15) * DMODEL);                     \
        _Pragma("unroll")                                                                    \
        for (int ks = 0; ks < 2; ++ks)                                                       \
            _Pragma("unroll")                                                                \
            for (int dt = 0; dt < 2; ++dt)                                                   \
                VN[ks * 2 + dt] = ldbf8(vbase + (size_t)(dt * 16 + l15) * MkTot + tp + ks * 32 + lhi * 8); \
        _Pragma("unroll")                                                                    \
        for (int j = 0; j < 4; ++j)                                                          \
            MN[j] = *reinterpret_cast<const f32x4*>(mb + tp + j * 16 + lhi * 4);             \
        _Pragma("unroll")                                                                    \
        for (int g = 0; g < 4; ++g)                                                          \
            _Pragma("unroll")                                                                \
            for (int j = 0; j < 4; ++j) {                                                    \
                s[g][j][0] = EXP2(s[g][j][0]);                                               \
                s[g][j][1] = EXP2(s[g][j][1]);                                               \
                s[g][j][2] = EXP2(s[g][j][2]);                                               \
                s[g][j][3] = EXP2(s[g][j][3]);                                               \
            }                                                                                \
        asm volatile("" ::: "memory");                                                       \
        _Pragma("unroll")                                                                    \
        for (int g = 0; g < 4; ++g)                                                          \
            _Pragma("unroll")                                                                \
            for (int j = 0; j < 4; ++j) {                                                    \
                ushort4 w = make_ushort4(bfc(s[g][j][0]), bfc(s[g][j][1]),                   \
                                         bfc(s[g][j][2]), bfc(s[g][j][3]));                  \
                *reinterpret_cast<ushort4*>(&pt[wave][g * 16 + l15][(j * 16 + lhi * 4) ^ swz]) = w; \
            }                                                                                \
        asm volatile("" ::: "memory");                                                       \
        _Pragma("unroll")                                                                    \
        for (int ks = 0; ks < 2; ++ks) {                                                     \
            bf16x8 pa[4];                                                                    \
            _Pragma("unroll")                                                                \
            for (int g = 0; g < 4; ++g)                                                      \
                pa[g] = ldbf8(&pt[wave][g * 16 + l15][(ks * 32 + lhi * 8) ^ swz]);           \
            _Pragma("unroll")                                                                \
            for (int g = 0; g < 4; ++g) {                                                    \
                _Pragma("unroll")                                                            \
                for (int dt = 0; dt < 2; ++dt)                                               \
                    ctx[g][dt] = __builtin_amdgcn_mfma_f32_16x16x32_bf16(pa[g], VC[ks * 2 + dt], ctx[g][dt], 0, 0, 0); \
                ctxS[g] = __builtin_amdgcn_mfma_f32_16x16x32_bf16(pa[g], ones8, ctxS[g], 0, 0, 0); \
            }                                                                                \
        }                                                                                    \
    }

    const int NT = Sk >> 6;   // SA: 32, CA: 16 (even)
    for (int t = 0; t < NT; t += 2) {
        const int t1 = (t + 1) << 6;
        ATTN_STEP(kfA, vfA, mcA, kfB, vfB, mcB, t1);
        const int t2 = ((t + 2 < NT) ? t + 2 : t + 1) << 6;
        ATTN_STEP(kfB, vfB, mcB, kfA, vfA, mcA, t2);
    }
#undef ATTN_STEP

    // ---- epilogue ----
#pragma unroll
    for (int g = 0; g < 4; ++g)
#pragma unroll
        for (int r = 0; r < 4; ++r) {
            const float inv = 1.0f / ctxS[g][r];
            const int row = qrow0 + g * 16 + lhi * 4 + r;
#pragma unroll
            for (int dt = 0; dt < 2; ++dt)
                Ob[(size_t)row * DMODEL + colh + dt * 16 + l15] = bfc(ctx[g][dt][r] * inv);
        }
}

// ---------------- LayerNorm (fused residual add; optional 2nd LN; optional split-K sum) ----------------
template<bool DBL, bool WBF, bool SPLIT>
__global__ __launch_bounds__(256) void ln_kernel(
    const float* __restrict__ X, const float* __restrict__ X2, const float* __restrict__ Res,
    const float* __restrict__ g1p, const float* __restrict__ b1p,
    const float* __restrict__ g2p, const float* __restrict__ b2p,
    float* __restrict__ Of, u16* __restrict__ Oh)
{
    const int lane = threadIdx.x & 63;
    const int row = blockIdx.x * 4 + (threadIdx.x >> 6);
    const size_t base = (size_t)row * DMODEL + lane * 4;
    float4 x = *reinterpret_cast<const float4*>(X + base);
    float4 rr = *reinterpret_cast<const float4*>(Res + base);
    float v[4] = {x.x + rr.x, x.y + rr.y, x.z + rr.z, x.w + rr.w};
    if constexpr (SPLIT) {
        float4 x2 = *reinterpret_cast<const float4*>(X2 + base);
        v[0] += x2.x; v[1] += x2.y; v[2] += x2.z; v[3] += x2.w;
    }
    float s = v[0] + v[1] + v[2] + v[3];
    float q = v[0] * v[0] + v[1] * v[1] + v[2] * v[2] + v[3] * v[3];
#pragma unroll
    for (int m = 1; m < 64; m <<= 1) { s += __shfl_xor(s, m, 64); q += __shfl_xor(q, m, 64); }
    float mean = s * (1.0f / DMODEL);
    float rstd = rsqrtf(fmaxf(q * (1.0f / DMODEL) - mean * mean, 0.f) + LN_EPS);
    float4 g = *reinterpret_cast<const float4*>(g1p + lane * 4);
    float4 bb = *reinterpret_cast<const float4*>(b1p + lane * 4);
    float y[4];
    y[0] = (v[0] - mean) * rstd * g.x + bb.x;
    y[1] = (v[1] - mean) * rstd * g.y + bb.y;
    y[2] = (v[2] - mean) * rstd * g.z + bb.z;
    y[3] = (v[3] - mean) * rstd * g.w + bb.w;
    if constexpr (DBL) {
#pragma unroll
        for (int k2 = 0; k2 < 4; ++k2) y[k2] *= 2.0f;
        float s2 = y[0] + y[1] + y[2] + y[3];
        float q2 = y[0] * y[0] + y[1] * y[1] + y[2] * y[2] + y[3] * y[3];
#pragma unroll
        for (int m = 1; m < 64; m <<= 1) { s2 += __shfl_xor(s2, m, 64); q2 += __shfl_xor(q2, m, 64); }
        float mean2 = s2 * (1.0f / DMODEL);
        float rstd2 = rsqrtf(fmaxf(q2 * (1.0f / DMODEL) - mean2 * mean2, 0.f) + LN_EPS);
        float4 g2 = *reinterpret_cast<const float4*>(g2p + lane * 4);
        float4 b2 = *reinterpret_cast<const float4*>(b2p + lane * 4);
        y[0] = (y[0] - mean2) * rstd2 * g2.x + b2.x;
        y[1] = (y[1] - mean2) * rstd2 * g2.y + b2.y;
        y[2] = (y[2] - mean2) * rstd2 * g2.z + b2.z;
        y[3] = (y[3] - mean2) * rstd2 * g2.w + b2.w;
    }
    *reinterpret_cast<float4*>(Of + base) = make_float4(y[0], y[1], y[2], y[3]);
    if constexpr (WBF) {
        ushort4 o = make_ushort4(bfc(y[0]), bfc(y[1]), bfc(y[2]), bfc(y[3]));
        *reinterpret_cast<ushort4*>(Oh + base) = o;
    }
}

// ---------------- host-side orchestration ----------------
extern "C" void kernel_launch(void* const* d_in, const int* in_sizes, int n_in,
                              void* d_out, int out_size, void* d_ws, size_t ws_size,
                              hipStream_t stream) {
    constexpr size_t MB = 1u << 20;
    if (ws_size < 70 * MB) return;

    const float* vis   = (const float*)d_in[0];
    const float* txt   = (const float*)d_in[1];
    const float* vmask = (const float*)d_in[2];
    const float* tmask = (const float*)d_in[3];
    const float* sa_wq = (const float*)d_in[4];  const float* sa_bq = (const float*)d_in[5];
    const float* sa_wk = (const float*)d_in[6];  const float* sa_bk = (const float*)d_in[7];
    const float* sa_wv = (const float*)d_in[8];  const float* sa_bv = (const float*)d_in[9];
    const float* sa_wo = (const float*)d_in[10]; const float* sa_bo = (const float*)d_in[11];
    const float* ca_wq = (const float*)d_in[12]; const float* ca_bq = (const float*)d_in[13];
    const float* ca_wk = (const float*)d_in[14]; const float* ca_bk = (const float*)d_in[15];
    const float* ca_wv = (const float*)d_in[16]; const float* ca_bv = (const float*)d_in[17];
    const float* ca_wo = (const float*)d_in[18]; const float* ca_bo = (const float*)d_in[19];
    const float* ln1_g = (const float*)d_in[20]; const float* ln1_b = (const float*)d_in[21];
    const float* ln2_g = (const float*)d_in[22]; const float* ln2_b = (const float*)d_in[23];
    const float* ln3_g = (const float*)d_in[24]; const float* ln3_b = (const float*)d_in[25];
    const float* ln4_g = (const float*)d_in[26]; const float* ln4_b = (const float*)d_in[27];
    const float* fc1_w = (const float*)d_in[28]; const float* fc1_b = (const float*)d_in[29];
    const float* fc2_w = (const float*)d_in[30]; const float* fc2_b = (const float*)d_in[31];

    const int B = 4, Sq = 2048, St = 1024;
    const int Mq = B * Sq;   // 8192
    const int Mt = B * St;   // 4096

    char* ws = (char*)d_ws;
    u16*   q_bf    = (u16*)(ws + 6 * MB);
    u16*   k_bf    = (u16*)(ws + 10 * MB);
    u16*   vt_bf   = (u16*)(ws + 14 * MB);
    u16*   ctx_bf  = (u16*)(ws + 18 * MB);
    u16*   ffn1_bf = (u16*)(ws + 0);          // 32MB, overlaps (dead by FFN)
    float* attn_f  = (float*)(ws + 32 * MB);  // also ffn2a
    float* h1_f    = (float*)(ws + 40 * MB);  // also ffn2b
    u16*   h1_bf   = (u16*)(ws + 48 * MB);
    float* h3_f    = (float*)(ws + 52 * MB);
    u16*   h3_bf   = (u16*)(ws + 60 * MB);
    u16*   wts     = (u16*)(ws + 64 * MB);
    float* ffn2a   = attn_f;
    float* ffn2b   = h1_f;

    u16* wqkv_t = wts;                        // [768][256]
    u16* wkv_t  = wqkv_t + 768 * 256;         // [512][256]
    u16* cwq_t  = wkv_t + 512 * 256;
    u16* wo_t   = cwq_t + 65536;
    u16* cwo_t  = wo_t + 65536;
    u16* fc1_t  = cwo_t + 65536;              // [2048][256]
    u16* fc2_t  = fc1_t + 2048 * 256;         // [256][2048]
    float* vmask2 = (float*)(ws + 68 * MB);   // [4][2048] pre-scaled
    float* tmask2 = vmask2 + B * Sq;          // [4][1024]

    scale_mask<<<dim3((B * Sq + 255) / 256), 256, 0, stream>>>(vmask, vmask2, B * Sq);
    scale_mask<<<dim3((B * St + 255) / 256), 256, 0, stream>>>(tmask, tmask2, B * St);

    TArgs ta;
    ta.d[0] = {sa_wq, wqkv_t + 0 * 65536, 256, 256};
    ta.d[1] = {sa_wk, wqkv_t + 1 * 65536, 256, 256};
    ta.d[2] = {sa_wv, wqkv_t + 2 * 65536, 256, 256};
    ta.d[3] = {ca_wk, wkv_t + 0 * 65536, 256, 256};
    ta.d[4] = {ca_wv, wkv_t + 1 * 65536, 256, 256};
    ta.d[5] = {ca_wq, cwq_t, 256, 256};
    ta.d[6] = {sa_wo, wo_t, 256, 256};
    ta.d[7] = {ca_wo, cwo_t, 256, 256};
    ta.d[8] = {fc1_w, fc1_t, 256, 2048};
    ta.d[9] = {fc2_w, fc2_t, 2048, 256};
    transpose_cvt<<<dim3(512, 10), 256, 0, stream>>>(ta);

    // self-attention
    Slice sq = {q_bf, sa_bq, 1, QSCALE2}, sk = {k_bf, sa_bk, 1, 1.f}, sv = {vt_bf, sa_bv, 2, 1.f};
    gemm_xproj<<<dim3((Mq / 128) * 12), 256, 0, stream>>>(vis, wqkv_t, sq, sk, sv, Mq, Mq / 128);
    attn_kernel<<<dim3(B * HEADS * (Sq / 256)), 256, 0, stream>>>(q_bf, k_bf, vt_bf, vmask2, ctx_bf, Sq, Sq, Mq);
    gemm64<0, false><<<dim3((Mq / 64) * 4), 256, 0, stream>>>(ctx_bf, wo_t, sa_bo, attn_f, Mq, 256, 256, 4, 1.f);
    ln_kernel<false, true, false><<<dim3(Mq / 4), 256, 0, stream>>>(attn_f, nullptr, vis, ln1_g, ln1_b, nullptr, nullptr, h1_f, h1_bf);

    // cross-attention
    Slice ck = {k_bf, ca_bk, 1, 1.f}, cv = {vt_bf, ca_bv, 2, 1.f}, cd = {nullptr, nullptr, 1, 1.f};
    gemm_xproj<<<dim3((Mt / 128) * 8), 256, 0, stream>>>(txt, wkv_t, ck, cv, cd, Mt, Mt / 128);
    gemm64<1, false><<<dim3((Mq / 64) * 4), 256, 0, stream>>>(h1_bf, cwq_t, ca_bq, q_bf, Mq, 256, 256, 4, QSCALE2);
    attn_kernel<<<dim3(B * HEADS * (Sq / 256)), 256, 0, stream>>>(q_bf, k_bf, vt_bf, tmask2, ctx_bf, Sq, St, Mt);
    gemm64<0, false><<<dim3((Mq / 64) * 4), 256, 0, stream>>>(ctx_bf, cwo_t, ca_bo, attn_f, Mq, 256, 256, 4, 1.f);
    ln_kernel<true, true, false><<<dim3(Mq / 4), 256, 0, stream>>>(attn_f, nullptr, h1_f, ln2_g, ln2_b, ln3_g, ln3_b, h3_f, h3_bf);

    // FFN: wide GEMM for FC1, 128x64 split-K2 with dist-2 for FC2, LN4 sums halves
    gemm_wide<1, true><<<dim3((Mq / 128) * 16), 256, 0, stream>>>(h3_bf, fc1_t, fc1_b, ffn1_bf, Mq, 2048, 256, Mq / 128, 1.f);
    gemm_sk2<<<dim3((Mq / 128) * 4 * 2), 256, 0, stream>>>(ffn1_bf, fc2_t, fc2_b, ffn2a, Mq, 256, 2048, 1024, Mq / 128);
    ln_kernel<false, false, true><<<dim3(Mq / 4), 256, 0, stream>>>(ffn2a, ffn2b, h3_f, ln4_g, ln4_b, nullptr, nullptr, (float*)d_out, nullptr);
}